// Round 7
// baseline (1207.534 us; speedup 1.0000x reference)
//
#include <hip/hip_runtime.h>

#define LMAX   10
#define BATCH  16384
#define NCOLS  381
#define NF     121
#define NPAIRS 66

typedef __attribute__((ext_vector_type(8))) short    short8;
typedef __attribute__((ext_vector_type(8))) _Float16 half8;
typedef __attribute__((ext_vector_type(2))) _Float16 half2v;
typedef __attribute__((ext_vector_type(4))) float    floatx4;
typedef __attribute__((ext_vector_type(4))) unsigned uint4v;

__device__ __forceinline__ short f32_to_f16_bits(float x) {
    return __builtin_bit_cast(short, (_Float16)x);   // RNE
}

// ---------------------------------------------------------------------------
// JOB decomposition: each pair (l1,l2) is split into jobs covering an l-range
// [la,lb] whose total output width sum(2l+1) <= 64  (greedy; always <=2 jobs,
// so every job has ntj <= 4 accumulator tiles -> acc regs 32, no spill, and
// launch_bounds(256,5) is safe).  cg16 is laid out PER JOB in fragment-order
// slabs: slab(pan,n0) = 512 halves, interior [quad][r16][j] so a wave's
// per-slab load/read is contiguous 1KB (lane*16B), zero bank conflicts.
// ---------------------------------------------------------------------------
__device__ __forceinline__ void decode_job(int p, int& l1, int& l2,
                                           int& la, int& lb,
                                           long long& off, int& colbase,
                                           int& c16off, int& ntj)
{
    long long o = 0; int cb = 0, c16 = 0, idx = 0;
    for (int a = 0; a <= LMAX; ++a) {
        for (int bq = a; bq <= LMAX; ++bq) {
            const int d    = (2*a+1)*(2*bq+1);
            const int lmin = bq - a;
            const int lmx  = (a + bq < LMAX) ? (a + bq) : LMAX;
            const int npan = (d + 31) >> 5;
            int ls = lmin;
            while (ls <= lmx) {
                int wsum = 0, lc = ls, le = ls;
                while (lc <= lmx && wsum + 2*lc + 1 <= 64) {
                    wsum += 2*lc + 1; le = lc; ++lc;
                }
                const int nt = (wsum + 15) >> 4;
                if (idx == p) {
                    l1 = a; l2 = bq; la = ls; lb = le; off = o;
                    colbase = cb + (ls - lmin); c16off = c16; ntj = nt;
                    return;
                }
                c16 += nt * 16 * npan * 32; ++idx; ls = lc;
            }
            o += (long long)d * d; cb += lmx - lmin + 1;
        }
    }
    l1 = l2 = 0; la = lb = 0; off = 0; colbase = 0; c16off = 0; ntj = 1;
}

// ---------------------------------------------------------------------------
// prep kernel = build_f (coalesced, LDS-staged) + per-job cg_to_f16.
//  blocks [0,512):          build_f, btile = bid*32.
//  blocks [512,512+7*njobs): cg16 writer, job = bid2/7, xk = bid2%7.
// ---------------------------------------------------------------------------
__global__ __launch_bounds__(256) void prep(const float* __restrict__ cre,
                                            const float* __restrict__ cim,
                                            const float* __restrict__ cg,
                                            float2* __restrict__ f,
                                            short* __restrict__ cg16)
{
    __shared__ float sr[32 * 121];
    __shared__ float si[32 * 121];
    const int tid = threadIdx.x;

    if (blockIdx.x < 512) {
        // ---- build_f part ----
        const int btile = blockIdx.x * 32;
        for (int t = tid; t < 32 * 121; t += 256) {
            sr[t] = cre[(size_t)btile * 121 + t];
            si[t] = cim[(size_t)btile * 121 + t];
        }
        __syncthreads();
        for (int task = tid; task < 32 * 121; task += 256) {
            const int row = task & 31;
            const int idx = task >> 5;
            int l = (int)sqrtf((float)idx + 0.5f);
            if (l * l > idx) --l;
            if ((l + 1) * (l + 1) <= idx) ++l;
            const int m = idx - l * l - l;
            const float* crow  = sr + row * 121 + l * 11;
            const float* cirow = si + row * 121 + l * 11;
            float re, im;
            if (m >= 0) { re = crow[m]; im = cirow[m]; }
            else {
                const int a = -m;
                const float sg = (a & 1) ? -1.0f : 1.0f;
                re = sg * crow[a]; im = -sg * cirow[a];
            }
            f[(size_t)idx * BATCH + btile + row] = make_float2(re, im);
        }
        return;
    }

    // ---- per-job cg16 writer (fragment-order slabs) ----
    const int bid2 = blockIdx.x - 512;
    const int job = bid2 / 7;
    const int xk  = bid2 - job * 7;

    int l1, l2, la, lb, colbase, c16off, ntj; long long off;
    decode_job(job, l1, l2, la, lb, off, colbase, c16off, ntj);
    const int d     = (2*l1+1)*(2*l2+1);
    const int lmin  = l2 - l1;
    const int npan  = (d + 31) >> 5;
    const int K32   = npan * 32;
    const int kbase = xk * 64;
    if (kbase >= K32) return;
    const int kend  = (kbase + 64 < K32) ? kbase + 64 : K32;
    const int nstart = la*la - lmin*lmin;          // job's first global col
    const int usedj  = (lb+1)*(lb+1) - la*la;      // job's used col count
    const int usedp  = ntj * 16;
    const int nn = tid & 127;
    const int kh = tid >> 7;
    if (nn >= usedp) return;
    const int n0   = nn >> 4;
    const int r16n = nn & 15;
    for (int k = kbase + kh; k < kend; k += 2) {
        float v = 0.f;
        if (nn < usedj && k < d)
            v = cg[off + (size_t)k * d + nstart + nn];
        const int pan = k >> 5;
        const int kq  = (k >> 3) & 3;
        const int j   = k & 7;
        cg16[(size_t)c16off + ((size_t)(pan * ntj + n0) << 9)
             + (kq << 7) + (r16n << 3) + j] = f32_to_f16_bits(v);
    }
}

// ---------------------------------------------------------------------------
// MFMA job kernel, round 18:
//  - jobs (<=4 N-tiles) instead of pairs -> acc 32 regs, (256,5) w/o spill,
//    LDS 20.75KB -> 5-7 blocks/CU (was 3.5) for latency hiding.
//  - B: LDS-broadcast staging (the r1-winning form), one 1KB fragment-order
//    slab per wave per panel (wave w stages slab n0=w), double-buffered,
//    one barrier per panel; load+ds_write lane*16B = conflict-free.
//  - f12 [row][FS=51] replicated layout, guard-free A frags (verified).
//  - two-pass epilogue on T[64][65] (job-local cols), part[2].
// LDS union: { f12 13056 + B0/B1 2x4096 = 21248 , T 16640 } = 21248B.
// ---------------------------------------------------------------------------
template<int NT, bool BIGD2>
__device__ __forceinline__ void job_body(const float2* __restrict__ f,
                                         const short* __restrict__ cg16,
                                         float* __restrict__ out,
                                         short* smem, int btile,
                                         int l1, int l2, int la, int lb,
                                         int c16off, int colbase)
{
    const int d1 = 2*l1 + 1, d2 = 2*l2 + 1, d = d1 * d2;
    const int n_lj = lb - la + 1;
    const int q1 = l1*l1, q2 = l2*l2;
    const int npan = (d + 31) >> 5;

    const int tid  = threadIdx.x;
    const int lane = tid & 63;
    const int w    = tid >> 6;        // wave 0..3 -> M-tile
    const int quad = lane >> 4;
    const int r16  = lane & 15;

    constexpr int FS = 51;                         // f12 row stride (dwords, odd)
    unsigned* f12 = (unsigned*)smem;               // [64][FS] packed half2 {re,im}
    short* B0 = smem + 6528;                       // 13056B in, [NT<=4][512] halves
    short* B1 = B0 + 2048;

    // ---- stage f1 | replicated f2 per batch row (fills ALL FS slots) ----
    {
        const int srow = tid & 63;
        unsigned* frw = f12 + srow * FS;
        const float2* f1p = f + (size_t)q1 * BATCH + btile + srow;
        const float2* f2p = f + (size_t)q2 * BATCH + btile + srow;
        for (int mm = tid >> 6; mm < FS; mm += 4) {
            float2 v;
            if (mm < d1) v = f1p[(size_t)mm * BATCH];
            else {
                int m2s = mm - d1;
                while (m2s >= d2) m2s -= d2;
                v = f2p[(size_t)m2s * BATCH];
            }
            half2v h; h.x = (_Float16)v.x; h.y = (_Float16)v.y;
            frw[mm] = __builtin_bit_cast(unsigned, h);
        }
    }

    const short* cgbase = cg16 + (size_t)c16off;

    // ---- stage panel 0 (wave w stages slab n0=w; 1KB, lane*16B) ----
    short8 pf;
    if (w < NT) {
        pf = *(const short8*)(cgbase + ((size_t)w << 9) + (lane << 3));
        *(short8*)&B0[(w << 9) + (lane << 3)] = pf;
    }
    __syncthreads();            // covers f12 + B0

    floatx4 accR[NT], accI[NT];
#pragma unroll
    for (int i = 0; i < NT; ++i) {
        accR[i] = (floatx4)0.0f; accI[i] = (floatx4)0.0f;
    }

    const int arow = w * 16 + r16;                 // this lane's batch row
    const unsigned* frow = f12 + arow * FS;

    // incremental k -> (m1, m2) for this lane's quad (one divide per block)
    const int k0q = quad * 8;
    int m1 = k0q / d2;
    int m2 = k0q - m1 * d2;
    const int q32 = 32 / d2;
    const int r32 = 32 - q32 * d2;

    for (int pan = 0; pan < npan; ++pan) {
        short* Bc = (pan & 1) ? B1 : B0;
        short* Bn = (pan & 1) ? B0 : B1;

        // ---- issue next panel's slab load (no wait yet) ----
        const bool more = (pan + 1) < npan;
        if (more && w < NT)
            pf = *(const short8*)(cgbase + ((size_t)((pan + 1) * NT + w) << 9)
                                  + (lane << 3));

        // ---- A fragments (tp in f16), guard-free ----
        unsigned ar[4], ai[4];
        {
            const unsigned* cb = frow + d1 + m2;   // 8 contiguous dwords
            if (BIGD2) {
                // d2>=9: at most one m1 boundary inside the 8-group
                const unsigned a0 = frow[m1];
                const unsigned a1 = frow[m1 + 1];
                const int wpos = d2 - m2;          // first j using a1
#pragma unroll
                for (int t = 0; t < 4; ++t) {
                    unsigned r01[2];
#pragma unroll
                    for (int u = 0; u < 2; ++u) {
                        const int j = 2*t + u;
                        const unsigned ad = (j >= wpos) ? a1 : a0;
                        const half2v a = __builtin_bit_cast(half2v, ad);
                        const half2v c = __builtin_bit_cast(half2v, cb[j]);
                        const _Float16 tr = a.x * c.x - a.y * c.y;
                        const _Float16 ti = a.x * c.y + a.y * c.x;
                        half2v rr; rr.x = tr; rr.y = ti;
                        r01[u] = __builtin_bit_cast(unsigned, rr);
                    }
                    ar[t] = (r01[0] & 0xffffu) | (r01[1] << 16);
                    ai[t] = (r01[0] >> 16)    | (r01[1] & 0xffff0000u);
                }
            } else {
                // small d2 (<=7): per-j a walk; c still via replication
                int mm1 = m1, tcnt = m2;
#pragma unroll
                for (int t = 0; t < 4; ++t) {
                    unsigned r01[2];
#pragma unroll
                    for (int u = 0; u < 2; ++u) {
                        const int j = 2*t + u;
                        const half2v a = __builtin_bit_cast(half2v, frow[mm1]);
                        const half2v c = __builtin_bit_cast(half2v, cb[j]);
                        const _Float16 tr = a.x * c.x - a.y * c.y;
                        const _Float16 ti = a.x * c.y + a.y * c.x;
                        half2v rr; rr.x = tr; rr.y = ti;
                        r01[u] = __builtin_bit_cast(unsigned, rr);
                        if (++tcnt == d2) { tcnt = 0; ++mm1; }
                    }
                    ar[t] = (r01[0] & 0xffffu) | (r01[1] << 16);
                    ai[t] = (r01[0] >> 16)    | (r01[1] & 0xffff0000u);
                }
            }
        }
        const half8 are = __builtin_bit_cast(half8, (uint4v){ar[0], ar[1], ar[2], ar[3]});
        const half8 aim = __builtin_bit_cast(half8, (uint4v){ai[0], ai[1], ai[2], ai[3]});

        // advance (m1,m2) by K=32 for next panel
        m1 += q32; m2 += r32;
        if (m2 >= d2) { m2 -= d2; ++m1; }

        // ---- MFMA from current LDS buffer (lane*16B reads, conflict-free) ----
#pragma unroll
        for (int n0 = 0; n0 < NT; ++n0) {
            const short8 b16 = *(const short8*)&Bc[(n0 << 9) + (lane << 3)];
            const half8 bb = __builtin_bit_cast(half8, b16);
            accR[n0] = __builtin_amdgcn_mfma_f32_16x16x32_f16(are, bb, accR[n0], 0, 0, 0);
            accI[n0] = __builtin_amdgcn_mfma_f32_16x16x32_f16(aim, bb, accI[n0], 0, 0, 0);
        }

        // ---- commit next panel to alternate buffer, one barrier ----
        if (more && w < NT)
            *(short8*)&Bn[(w << 9) + (lane << 3)] = pf;
        __syncthreads();
    }

    // ---- two-pass fp32 epilogue; T[64][65] job-local cols, no col guard ----
    // C/D frag layout: col = n0*16 + r16 (<64), row = w*16 + quad*4 + r.
    float* T = (float*)smem;                  // [64][65] fp32 (16640B)
    const int ntask = 64 * n_lj;              // <= 512
    float part[2] = {0.f, 0.f};

    // pass 1: real
#pragma unroll
    for (int n0 = 0; n0 < NT; ++n0)
#pragma unroll
        for (int r = 0; r < 4; ++r)
            T[(w*16 + quad*4 + r) * 65 + n0*16 + r16] = accR[n0][r];
    __syncthreads();
    {
        int it = 0;
        for (int task = tid; task < ntask; task += 256, ++it) {
            const int trow = task & 63;
            const int li   = task >> 6;
            const int l    = la + li;
            const int sll  = l*l - la*la;      // job-local col of l-block
            const int W    = 2*l + 1;
            const int b    = btile + trow;
            const float* Trow = T + trow * 65 + sll;
            float acc = 0.f;
            for (int j = 0; j < W; ++j)
                acc = fmaf(Trow[j], f[(size_t)(l*l + j) * BATCH + b].x, acc);
            part[it] = acc;
        }
    }
    __syncthreads();

    // pass 2: imaginary
#pragma unroll
    for (int n0 = 0; n0 < NT; ++n0)
#pragma unroll
        for (int r = 0; r < 4; ++r)
            T[(w*16 + quad*4 + r) * 65 + n0*16 + r16] = accI[n0][r];
    __syncthreads();
    {
        int it = 0;
        for (int task = tid; task < ntask; task += 256, ++it) {
            const int trow = task & 63;
            const int li   = task >> 6;
            const int l    = la + li;
            const int sll  = l*l - la*la;
            const int W    = 2*l + 1;
            const int b    = btile + trow;
            const float* Trow = T + trow * 65 + sll;
            float acc = part[it];
            for (int j = 0; j < W; ++j)
                acc = fmaf(Trow[j], f[(size_t)(l*l + j) * BATCH + b].y, acc);
            out[(size_t)b * NCOLS + colbase + li] = acc;
        }
    }
}

__global__ __launch_bounds__(256, 5) void so3_mfma(const float2* __restrict__ f,
                                                   const short* __restrict__ cg16,
                                                   float* __restrict__ out)
{
    __shared__ __align__(16) short smem[10624];   // 21,248B
    const int btile = blockIdx.x * 64;
    const int p     = gridDim.y - 1 - blockIdx.y; // heavy jobs first (reverse)
    int l1, l2, la, lb, colbase, c16off, ntj; long long off;
    decode_job(p, l1, l2, la, lb, off, colbase, c16off, ntj);
    if (l2 >= 4) {   // d2 >= 9 -> single-boundary A path
        switch (ntj) {
            case 1: job_body<1,true >(f, cg16, out, smem, btile, l1, l2, la, lb, c16off, colbase); break;
            case 2: job_body<2,true >(f, cg16, out, smem, btile, l1, l2, la, lb, c16off, colbase); break;
            case 3: job_body<3,true >(f, cg16, out, smem, btile, l1, l2, la, lb, c16off, colbase); break;
            default: job_body<4,true >(f, cg16, out, smem, btile, l1, l2, la, lb, c16off, colbase); break;
        }
    } else {
        switch (ntj) {
            case 1: job_body<1,false>(f, cg16, out, smem, btile, l1, l2, la, lb, c16off, colbase); break;
            case 2: job_body<2,false>(f, cg16, out, smem, btile, l1, l2, la, lb, c16off, colbase); break;
            case 3: job_body<3,false>(f, cg16, out, smem, btile, l1, l2, la, lb, c16off, colbase); break;
            default: job_body<4,false>(f, cg16, out, smem, btile, l1, l2, la, lb, c16off, colbase); break;
        }
    }
}

// ---------------------------------------------------------------------------
// Full fallback (fp32 VALU, no workspace). Round-5 copy.
// ---------------------------------------------------------------------------
template<int L>
__device__ __forceinline__ float core_fb(const float2* f1v, const float2* f2v,
                                         const float2* flv,
                                         const float* __restrict__ cgp,
                                         int d1, int d2, int d)
{
    constexpr int W = 2*L + 1;
    float accr[W], acci[W];
#pragma unroll
    for (int k = 0; k < W; ++k) { accr[k] = 0.f; acci[k] = 0.f; }
    for (int m1 = 0; m1 < d1; ++m1) {
        const float2 a = f1v[m1];
        const float* rowbase = cgp + (size_t)m1 * d2 * d;
        for (int m2 = 0; m2 < d2; ++m2) {
            const float2 bb = f2v[m2];
            const float tr = a.x*bb.x - a.y*bb.y;
            const float ti = a.x*bb.y + a.y*bb.x;
            const float* row = rowbase + (size_t)m2 * d;
#pragma unroll
            for (int k = 0; k < W; ++k) {
                accr[k] = fmaf(tr, row[k], accr[k]);
                acci[k] = fmaf(ti, row[k], acci[k]);
            }
        }
    }
    float orr = 0.f;
#pragma unroll
    for (int k = 0; k < W; ++k)
        orr = fmaf(accr[k], flv[k].x, fmaf(acci[k], flv[k].y, orr));
    return orr;
}

__global__ __launch_bounds__(256) void so3_tp_direct(const float* __restrict__ cre,
                                                     const float* __restrict__ cim,
                                                     const float* __restrict__ cg,
                                                     float* __restrict__ out)
{
    const int b = blockIdx.x * blockDim.x + threadIdx.x;
    const int t = blockIdx.y;
    int l1 = 0, l2 = 0, l = 0; long long off = 0;
    {
        int tt = t; long long o = 0;
        bool found = false;
        for (int a = 0; a <= LMAX && !found; ++a)
            for (int bq = a; bq <= LMAX && !found; ++bq) {
                const int d = (2*a+1)*(2*bq+1);
                const int lmin = bq - a;
                const int lmx = (a+bq < LMAX) ? (a+bq) : LMAX;
                const int cnt = lmx - lmin + 1;
                if (tt < cnt) { l1 = a; l2 = bq; l = lmin + tt; off = o; found = true; }
                else { tt -= cnt; o += (long long)d*d; }
            }
    }
    const int d1 = 2*l1+1, d2 = 2*l2+1, d = d1*d2;
    const int lmin = l2 - l1;
    const int s = l*l - lmin*lmin;

    const float* cr = cre + (size_t)b * 121;
    const float* ci = cim + (size_t)b * 121;
    float2 f1v[21], f2v[21], flv[21];
    for (int j = 0; j <= 2*l1; ++j) {
        const int m = j - l1;
        if (m >= 0) f1v[j] = make_float2(cr[l1*11+m], ci[l1*11+m]);
        else { const int a2 = -m; const float sg = (a2&1)?-1.f:1.f;
               f1v[j] = make_float2(sg*cr[l1*11+a2], -sg*ci[l1*11+a2]); }
    }
    for (int j = 0; j <= 2*l2; ++j) {
        const int m = j - l2;
        if (m >= 0) f2v[j] = make_float2(cr[l2*11+m], ci[l2*11+m]);
        else { const int a2 = -m; const float sg = (a2&1)?-1.f:1.f;
               f2v[j] = make_float2(sg*cr[l2*11+a2], -sg*ci[l2*11+a2]); }
    }
    for (int j = 0; j <= 2*l; ++j) {
        const int m = j - l;
        if (m >= 0) flv[j] = make_float2(cr[l*11+m], ci[l*11+m]);
        else { const int a2 = -m; const float sg = (a2&1)?-1.f:1.f;
               flv[j] = make_float2(sg*cr[l*11+a2], -sg*ci[l*11+a2]); }
    }
    const float* cgp = cg + off + s;
    float r;
    switch (l) {
        case 0: r = core_fb<0>(f1v,f2v,flv,cgp,d1,d2,d); break;
        case 1: r = core_fb<1>(f1v,f2v,flv,cgp,d1,d2,d); break;
        case 2: r = core_fb<2>(f1v,f2v,flv,cgp,d1,d2,d); break;
        case 3: r = core_fb<3>(f1v,f2v,flv,cgp,d1,d2,d); break;
        case 4: r = core_fb<4>(f1v,f2v,flv,cgp,d1,d2,d); break;
        case 5: r = core_fb<5>(f1v,f2v,flv,cgp,d1,d2,d); break;
        case 6: r = core_fb<6>(f1v,f2v,flv,cgp,d1,d2,d); break;
        case 7: r = core_fb<7>(f1v,f2v,flv,cgp,d1,d2,d); break;
        case 8: r = core_fb<8>(f1v,f2v,flv,cgp,d1,d2,d); break;
        case 9: r = core_fb<9>(f1v,f2v,flv,cgp,d1,d2,d); break;
        default: r = core_fb<10>(f1v,f2v,flv,cgp,d1,d2,d); break;
    }
    out[(size_t)b * NCOLS + t] = r;
}

// ---------------------------------------------------------------------------
extern "C" void kernel_launch(void* const* d_in, const int* in_sizes, int n_in,
                              void* d_out, int out_size, void* d_ws, size_t ws_size,
                              hipStream_t stream)
{
    const float* cre = (const float*)d_in[0];
    const float* cim = (const float*)d_in[1];
    const float* cg  = (const float*)d_in[2];
    float* out = (float*)d_out;

    // host mirror of decode_job walk: count jobs + cg16 total size
    long long c16_total = 0; int njobs = 0;
    for (int l1 = 0; l1 <= LMAX; ++l1)
        for (int l2 = l1; l2 <= LMAX; ++l2) {
            const int d    = (2*l1+1)*(2*l2+1);
            const int lmin = l2 - l1;
            const int lmx  = (l1 + l2 < LMAX) ? (l1 + l2) : LMAX;
            const int npan = (d + 31) >> 5;
            int ls = lmin;
            while (ls <= lmx) {
                int wsum = 0, lc = ls;
                while (lc <= lmx && wsum + 2*lc + 1 <= 64) { wsum += 2*lc + 1; ++lc; }
                c16_total += (long long)((wsum + 15) / 16) * 16 * npan * 32;
                ++njobs; ls = lc;
            }
        }

    const size_t f_bytes = (size_t)NF * BATCH * sizeof(float2);   // 15,859,712
    const size_t need    = f_bytes + (size_t)c16_total * 2;

    if (ws_size >= need) {
        float2* f    = (float2*)d_ws;
        short*  cg16 = (short*)((char*)d_ws + f_bytes);
        prep    <<<dim3(512 + 7 * njobs), 256, 0, stream>>>(cre, cim, cg, f, cg16);
        so3_mfma<<<dim3(BATCH/64, njobs), 256, 0, stream>>>(f, cg16, out);
    } else {
        so3_tp_direct<<<dim3(BATCH/256, NCOLS), 256, 0, stream>>>(cre, cim, cg, out);
    }
}

// Round 8
// 347.673 us; speedup vs baseline: 3.4732x; 3.4732x over previous
//
#include <hip/hip_runtime.h>

#define LMAX   10
#define BATCH  16384
#define NCOLS  381
#define NF     121
#define NPAIRS 66

typedef __attribute__((ext_vector_type(8))) short    short8;
typedef __attribute__((ext_vector_type(8))) _Float16 half8;
typedef __attribute__((ext_vector_type(2))) _Float16 half2v;
typedef __attribute__((ext_vector_type(4))) float    floatx4;
typedef __attribute__((ext_vector_type(4))) unsigned uint4v;

__device__ __forceinline__ short f32_to_f16_bits(float x) {
    return __builtin_bit_cast(short, (_Float16)x);   // RNE
}

// heavy-pairs-first dispatch order (sorted by descending npan*NT)
__device__ const int kPairOrder[NPAIRS] = {
    65,64,63,62,61,60,58,59,56,57,55,52,53,54,49,51,47,50,48,46,
    43,44,41,42,40,45,36,34,39,37,35,27,33,38,29,25,26,28,32,18,
    19,24,30,31,15,16,17,20,22,23,14, 8, 9,10,21, 0, 1, 2, 3, 4,
     5, 6, 7,11,12,13
};

// pair index p -> (l1, l2, cg offset, first output column, cg16 offset)
__device__ __forceinline__ void decode_pair_ext(int p, int& l1, int& l2,
                                                long long& off, int& colbase,
                                                int& c16off)
{
    long long o = 0; int cb = 0, c16 = 0, idx = 0;
    for (int a = 0; a <= LMAX; ++a) {
        for (int bq = a; bq <= LMAX; ++bq) {
            const int d    = (2*a+1)*(2*bq+1);
            const int lmin = bq - a;
            const int lmx  = (a + bq < LMAX) ? (a + bq) : LMAX;
            const int used = (lmx+1)*(lmx+1) - lmin*lmin;
            const int npan = (d + 31) >> 5;
            const int nt   = (used + 15) >> 4;
            if (idx == p) { l1 = a; l2 = bq; off = o; colbase = cb; c16off = c16; return; }
            o += (long long)d * d; cb += lmx - lmin + 1;
            c16 += nt * 16 * npan * 32; ++idx;
        }
    }
    l1 = l2 = 0; off = 0; colbase = 0; c16off = 0;
}

// ---------------------------------------------------------------------------
// prep kernel = build_f (coalesced, LDS-staged) + cg_to_f16, fused (r3-verified).
//  blocks [0,512):   build_f, btile = bid*32.
//  blocks [512,974): cg_to_f16 -> [n][K32] layout (r1-consumer order).
// ---------------------------------------------------------------------------
__global__ __launch_bounds__(256) void prep(const float* __restrict__ cre,
                                            const float* __restrict__ cim,
                                            const float* __restrict__ cg,
                                            float2* __restrict__ f,
                                            short* __restrict__ cg16)
{
    __shared__ float sr[32 * 121];
    __shared__ float si[32 * 121];
    const int tid = threadIdx.x;

    if (blockIdx.x < 512) {
        // ---- build_f part ----
        const int btile = blockIdx.x * 32;
        for (int t = tid; t < 32 * 121; t += 256) {
            sr[t] = cre[(size_t)btile * 121 + t];
            si[t] = cim[(size_t)btile * 121 + t];
        }
        __syncthreads();
        for (int task = tid; task < 32 * 121; task += 256) {
            const int row = task & 31;
            const int idx = task >> 5;
            int l = (int)sqrtf((float)idx + 0.5f);
            if (l * l > idx) --l;
            if ((l + 1) * (l + 1) <= idx) ++l;
            const int m = idx - l * l - l;
            const float* crow  = sr + row * 121 + l * 11;
            const float* cirow = si + row * 121 + l * 11;
            float re, im;
            if (m >= 0) { re = crow[m]; im = cirow[m]; }
            else {
                const int a = -m;
                const float sg = (a & 1) ? -1.0f : 1.0f;
                re = sg * crow[a]; im = -sg * cirow[a];
            }
            f[(size_t)idx * BATCH + btile + row] = make_float2(re, im);
        }
        return;
    }

    // ---- cg_to_f16 part ([n][K32] layout) ----
    const int bid2 = blockIdx.x - 512;
    const int pair = bid2 / 7;
    const int xk   = bid2 - pair * 7;

    int l1, l2, colbase, c16off; long long off;
    decode_pair_ext(pair, l1, l2, off, colbase, c16off);
    const int d    = (2*l1+1)*(2*l2+1);
    const int lmin = l2 - l1;
    const int lmx  = (l1 + l2 < LMAX) ? (l1 + l2) : LMAX;
    const int used = (lmx+1)*(lmx+1) - lmin*lmin;
    const int npan = (d + 31) >> 5;
    const int nt   = (used + 15) >> 4;
    const int K32  = npan * 32;
    const int kbase = xk * 64;
    if (kbase >= K32) return;
    const int kend  = (kbase + 64 < K32) ? kbase + 64 : K32;
    const int usedp = nt * 16;
    const int nn = tid & 127;
    const int kh = tid >> 7;
    if (nn >= usedp) return;
    for (int k = kbase + kh; k < kend; k += 2) {
        float v = 0.f;
        if (nn < used && k < d)
            v = cg[off + (size_t)k * d + nn];
        cg16[(size_t)c16off + (size_t)nn * K32 + k] = f32_to_f16_bits(v);
    }
}

// ---------------------------------------------------------------------------
// MFMA pair kernel, round 20 = verified optimum assembly:
//  - r1/r3 panel loop: f12 [row][FS=51] replicated layout, guard-free A frags,
//    B [128][32] XOR-swizzled LDS-broadcast staging, double-buffered,
//    one barrier per panel, NT up to 8 (wide K-loop amortizes the chain).
//  - r1's verified two-pass epilogue (T[64][123] fp32, part[3]).
//  - __launch_bounds__(256,4): r2 proved (256,5) spills NT=7/8 (VGPR 48,
//    WRITE +111MB, dur +56us). r7 proved narrow NT panels are overhead-
//    dominated regardless of occupancy. Do not re-try either.
// LDS union: { f12 13056 + B0/B1 2x8192 = 29440 , T 31488 } = 31488B.
// ---------------------------------------------------------------------------
template<int NT, bool BIGD2>
__device__ __forceinline__ void pair_body(const float2* __restrict__ f,
                                          const short* __restrict__ cg16,
                                          float* __restrict__ out,
                                          short* smem, int btile,
                                          int l1, int l2, int c16off, int colbase)
{
    const int d1 = 2*l1 + 1, d2 = 2*l2 + 1, d = d1 * d2;
    const int lmin = l2 - l1;
    const int lmx  = (l1 + l2 < LMAX) ? (l1 + l2) : LMAX;
    const int n_l  = lmx - lmin + 1;
    const int q1 = l1*l1, q2 = l2*l2;
    const int npan = (d + 31) >> 5;
    const int K32  = npan * 32;

    const int tid  = threadIdx.x;
    const int lane = tid & 63;
    const int w    = tid >> 6;        // wave 0..3 -> M-tile
    const int quad = lane >> 4;
    const int r16  = lane & 15;

    constexpr int FS = 51;                         // f12 row stride (dwords, odd)
    unsigned* f12 = (unsigned*)smem;               // [64][FS] packed half2 {re,im}
    short* B0 = smem + 64 * FS * 2;                // 13056 B in (16B aligned)
    short* B1 = B0 + 128 * 32;                     // each [128 rows][32 k] swizzled

    // ---- stage f1 | replicated f2 per batch row (fills ALL FS slots) ----
    {
        const int srow = tid & 63;
        unsigned* frw = f12 + srow * FS;
        const float2* f1p = f + (size_t)q1 * BATCH + btile + srow;
        const float2* f2p = f + (size_t)q2 * BATCH + btile + srow;
        for (int mm = tid >> 6; mm < FS; mm += 4) {
            float2 v;
            if (mm < d1) v = f1p[(size_t)mm * BATCH];
            else {
                int m2s = mm - d1;
                while (m2s >= d2) m2s -= d2;
                v = f2p[(size_t)m2s * BATCH];
            }
            half2v h; h.x = (_Float16)v.x; h.y = (_Float16)v.y;
            frw[mm] = __builtin_bit_cast(unsigned, h);
        }
    }

    const short* cgbase = cg16 + (size_t)c16off;
    const int nchunk = NT * 64;                    // 16B chunks per panel (<=512)

    // B prefetch: issue (global->regs) and commit (regs->LDS); XOR swizzle
    short8 pf0, pf1;
    const int ch0 = tid, ch1 = tid + 256;
    const int nr0 = ch0 >> 2, cc0 = ch0 & 3;
    const int nr1 = ch1 >> 2, cc1 = ch1 & 3;
    const size_t so0 = (size_t)nr0 * K32 + cc0 * 8;
    const size_t so1 = (size_t)nr1 * K32 + cc1 * 8;
    const int bo0 = nr0 * 32 + (((cc0 + (nr0 >> 1)) & 3) << 3);
    const int bo1 = nr1 * 32 + (((cc1 + (nr1 >> 1)) & 3) << 3);

    // panel 0 into B0 (overlaps f12 staging above; barrier covers both)
    if (ch0 < nchunk) pf0 = *(const short8*)(cgbase + so0);
    if (ch1 < nchunk) pf1 = *(const short8*)(cgbase + so1);
    if (ch0 < nchunk) *(short8*)&B0[bo0] = pf0;
    if (ch1 < nchunk) *(short8*)&B0[bo1] = pf1;
    __syncthreads();

    floatx4 accR[NT], accI[NT];
#pragma unroll
    for (int i = 0; i < NT; ++i) {
        accR[i] = (floatx4)0.0f; accI[i] = (floatx4)0.0f;
    }

    const int arow = w * 16 + r16;                 // this lane's batch row
    const unsigned* frow = f12 + arow * FS;
    const int bswz = ((quad + (r16 >> 1)) & 3) << 3;   // B read chunk swizzle

    // incremental k -> (m1, m2) for this lane's quad (one divide per block)
    const int k0q = quad * 8;
    int m1 = k0q / d2;
    int m2 = k0q - m1 * d2;
    const int q32 = 32 / d2;
    const int r32 = 32 - q32 * d2;

    for (int pan = 0; pan < npan; ++pan) {
        short* Bc = (pan & 1) ? B1 : B0;
        short* Bn = (pan & 1) ? B0 : B1;

        // ---- issue next panel's global loads (no wait yet) ----
        const bool more = (pan + 1) < npan;
        if (more) {
            const size_t kn = (size_t)(pan + 1) << 5;
            if (ch0 < nchunk) pf0 = *(const short8*)(cgbase + so0 + kn);
            if (ch1 < nchunk) pf1 = *(const short8*)(cgbase + so1 + kn);
        }

        // ---- A fragments (tp in f16), guard-free ----
        unsigned ar[4], ai[4];
        {
            const unsigned* cb = frow + d1 + m2;   // 8 contiguous dwords
            if (BIGD2) {
                // d2>=9: at most one m1 boundary inside the 8-group
                const unsigned a0 = frow[m1];
                const unsigned a1 = frow[m1 + 1];
                const int wpos = d2 - m2;          // first j using a1
#pragma unroll
                for (int t = 0; t < 4; ++t) {
                    unsigned r01[2];
#pragma unroll
                    for (int u = 0; u < 2; ++u) {
                        const int j = 2*t + u;
                        const unsigned ad = (j >= wpos) ? a1 : a0;
                        const half2v a = __builtin_bit_cast(half2v, ad);
                        const half2v c = __builtin_bit_cast(half2v, cb[j]);
                        const _Float16 tr = a.x * c.x - a.y * c.y;
                        const _Float16 ti = a.x * c.y + a.y * c.x;
                        half2v rr; rr.x = tr; rr.y = ti;
                        r01[u] = __builtin_bit_cast(unsigned, rr);
                    }
                    ar[t] = (r01[0] & 0xffffu) | (r01[1] << 16);
                    ai[t] = (r01[0] >> 16)    | (r01[1] & 0xffff0000u);
                }
            } else {
                // small d2 (<=7): per-j a walk; c still via replication
                int mm1 = m1, tcnt = m2;
#pragma unroll
                for (int t = 0; t < 4; ++t) {
                    unsigned r01[2];
#pragma unroll
                    for (int u = 0; u < 2; ++u) {
                        const int j = 2*t + u;
                        const half2v a = __builtin_bit_cast(half2v, frow[mm1]);
                        const half2v c = __builtin_bit_cast(half2v, cb[j]);
                        const _Float16 tr = a.x * c.x - a.y * c.y;
                        const _Float16 ti = a.x * c.y + a.y * c.x;
                        half2v rr; rr.x = tr; rr.y = ti;
                        r01[u] = __builtin_bit_cast(unsigned, rr);
                        if (++tcnt == d2) { tcnt = 0; ++mm1; }
                    }
                    ar[t] = (r01[0] & 0xffffu) | (r01[1] << 16);
                    ai[t] = (r01[0] >> 16)    | (r01[1] & 0xffff0000u);
                }
            }
        }
        const half8 are = __builtin_bit_cast(half8, (uint4v){ar[0], ar[1], ar[2], ar[3]});
        const half8 aim = __builtin_bit_cast(half8, (uint4v){ai[0], ai[1], ai[2], ai[3]});

        // advance (m1,m2) by K=32 for next panel
        m1 += q32; m2 += r32;
        if (m2 >= d2) { m2 -= d2; ++m1; }

        // ---- MFMA from current LDS buffer ----
#pragma unroll
        for (int n0 = 0; n0 < NT; ++n0) {
            const short8 b16 = *(const short8*)&Bc[(n0 * 16 + r16) * 32 + bswz];
            const half8 bb = __builtin_bit_cast(half8, b16);
            accR[n0] = __builtin_amdgcn_mfma_f32_16x16x32_f16(are, bb, accR[n0], 0, 0, 0);
            accI[n0] = __builtin_amdgcn_mfma_f32_16x16x32_f16(aim, bb, accI[n0], 0, 0, 0);
        }

        // ---- commit next panel to alternate buffer, one barrier ----
        if (more) {
            if (ch0 < nchunk) *(short8*)&Bn[bo0] = pf0;
            if (ch1 < nchunk) *(short8*)&Bn[bo1] = pf1;
        }
        __syncthreads();
    }

    // ---- two-pass fp32 epilogue (r1-verified); C/D: col=lane&15, row=quad*4+reg
    float* T = (float*)smem;                  // [64][123] fp32
    const int ntask = 64 * n_l;
    float part[3] = {0.f, 0.f, 0.f};

    // pass 1: real
#pragma unroll
    for (int n0 = 0; n0 < NT; ++n0)
#pragma unroll
        for (int r = 0; r < 4; ++r) {
            const int col = n0*16 + r16;
            if (col < 123)
                T[(w*16 + quad*4 + r) * 123 + col] = accR[n0][r];
        }
    __syncthreads();
    {
        int it = 0;
        for (int task = tid; task < ntask; task += 256, ++it) {
            const int trow = task & 63;
            const int li   = task >> 6;
            const int l    = lmin + li;
            const int sl   = l*l - lmin*lmin;
            const int W    = 2*l + 1;
            const int b    = btile + trow;
            const float* Trow = T + trow * 123 + sl;
            float acc = 0.f;
            for (int j = 0; j < W; ++j)
                acc = fmaf(Trow[j], f[(size_t)(l*l + j) * BATCH + b].x, acc);
            part[it] = acc;
        }
    }
    __syncthreads();

    // pass 2: imaginary
#pragma unroll
    for (int n0 = 0; n0 < NT; ++n0)
#pragma unroll
        for (int r = 0; r < 4; ++r) {
            const int col = n0*16 + r16;
            if (col < 123)
                T[(w*16 + quad*4 + r) * 123 + col] = accI[n0][r];
        }
    __syncthreads();
    {
        int it = 0;
        for (int task = tid; task < ntask; task += 256, ++it) {
            const int trow = task & 63;
            const int li   = task >> 6;
            const int l    = lmin + li;
            const int sl   = l*l - lmin*lmin;
            const int W    = 2*l + 1;
            const int b    = btile + trow;
            const float* Trow = T + trow * 123 + sl;
            float acc = part[it];
            for (int j = 0; j < W; ++j)
                acc = fmaf(Trow[j], f[(size_t)(l*l + j) * BATCH + b].y, acc);
            out[(size_t)b * NCOLS + colbase + li] = acc;
        }
    }
}

__global__ __launch_bounds__(256, 4) void so3_mfma(const float2* __restrict__ f,
                                                   const short* __restrict__ cg16,
                                                   float* __restrict__ out)
{
    __shared__ __align__(16) short smem[15744];   // 31.5 KB
    const int btile = blockIdx.x * 64;
    const int p     = kPairOrder[blockIdx.y];     // heavy pairs first
    int l1, l2, colbase, c16off; long long off;
    decode_pair_ext(p, l1, l2, off, colbase, c16off);
    const int lmin = l2 - l1;
    const int lmx  = (l1 + l2 < LMAX) ? (l1 + l2) : LMAX;
    const int used = (lmx+1)*(lmx+1) - lmin*lmin;
    const int nt   = (used + 15) >> 4;
    if (l2 >= 4) {   // d2 >= 9 -> single-boundary A path
        switch (nt) {
            case 1: pair_body<1,true>(f, cg16, out, smem, btile, l1, l2, c16off, colbase); break;
            case 2: pair_body<2,true>(f, cg16, out, smem, btile, l1, l2, c16off, colbase); break;
            case 3: pair_body<3,true>(f, cg16, out, smem, btile, l1, l2, c16off, colbase); break;
            case 4: pair_body<4,true>(f, cg16, out, smem, btile, l1, l2, c16off, colbase); break;
            case 5: pair_body<5,true>(f, cg16, out, smem, btile, l1, l2, c16off, colbase); break;
            case 6: pair_body<6,true>(f, cg16, out, smem, btile, l1, l2, c16off, colbase); break;
            case 7: pair_body<7,true>(f, cg16, out, smem, btile, l1, l2, c16off, colbase); break;
            default: pair_body<8,true>(f, cg16, out, smem, btile, l1, l2, c16off, colbase); break;
        }
    } else {         // l2 <= 3 -> nt <= 4
        switch (nt) {
            case 1: pair_body<1,false>(f, cg16, out, smem, btile, l1, l2, c16off, colbase); break;
            case 2: pair_body<2,false>(f, cg16, out, smem, btile, l1, l2, c16off, colbase); break;
            case 3: pair_body<3,false>(f, cg16, out, smem, btile, l1, l2, c16off, colbase); break;
            default: pair_body<4,false>(f, cg16, out, smem, btile, l1, l2, c16off, colbase); break;
        }
    }
}

// ---------------------------------------------------------------------------
// Full fallback (fp32 VALU, no workspace). Round-5 copy.
// ---------------------------------------------------------------------------
template<int L>
__device__ __forceinline__ float core_fb(const float2* f1v, const float2* f2v,
                                         const float2* flv,
                                         const float* __restrict__ cgp,
                                         int d1, int d2, int d)
{
    constexpr int W = 2*L + 1;
    float accr[W], acci[W];
#pragma unroll
    for (int k = 0; k < W; ++k) { accr[k] = 0.f; acci[k] = 0.f; }
    for (int m1 = 0; m1 < d1; ++m1) {
        const float2 a = f1v[m1];
        const float* rowbase = cgp + (size_t)m1 * d2 * d;
        for (int m2 = 0; m2 < d2; ++m2) {
            const float2 bb = f2v[m2];
            const float tr = a.x*bb.x - a.y*bb.y;
            const float ti = a.x*bb.y + a.y*bb.x;
            const float* row = rowbase + (size_t)m2 * d;
#pragma unroll
            for (int k = 0; k < W; ++k) {
                accr[k] = fmaf(tr, row[k], accr[k]);
                acci[k] = fmaf(ti, row[k], acci[k]);
            }
        }
    }
    float orr = 0.f;
#pragma unroll
    for (int k = 0; k < W; ++k)
        orr = fmaf(accr[k], flv[k].x, fmaf(acci[k], flv[k].y, orr));
    return orr;
}

__global__ __launch_bounds__(256) void so3_tp_direct(const float* __restrict__ cre,
                                                     const float* __restrict__ cim,
                                                     const float* __restrict__ cg,
                                                     float* __restrict__ out)
{
    const int b = blockIdx.x * blockDim.x + threadIdx.x;
    const int t = blockIdx.y;
    int l1 = 0, l2 = 0, l = 0; long long off = 0;
    {
        int tt = t; long long o = 0;
        bool found = false;
        for (int a = 0; a <= LMAX && !found; ++a)
            for (int bq = a; bq <= LMAX && !found; ++bq) {
                const int d = (2*a+1)*(2*bq+1);
                const int lmin = bq - a;
                const int lmx = (a+bq < LMAX) ? (a+bq) : LMAX;
                const int cnt = lmx - lmin + 1;
                if (tt < cnt) { l1 = a; l2 = bq; l = lmin + tt; off = o; found = true; }
                else { tt -= cnt; o += (long long)d*d; }
            }
    }
    const int d1 = 2*l1+1, d2 = 2*l2+1, d = d1*d2;
    const int lmin = l2 - l1;
    const int s = l*l - lmin*lmin;

    const float* cr = cre + (size_t)b * 121;
    const float* ci = cim + (size_t)b * 121;
    float2 f1v[21], f2v[21], flv[21];
    for (int j = 0; j <= 2*l1; ++j) {
        const int m = j - l1;
        if (m >= 0) f1v[j] = make_float2(cr[l1*11+m], ci[l1*11+m]);
        else { const int a2 = -m; const float sg = (a2&1)?-1.f:1.f;
               f1v[j] = make_float2(sg*cr[l1*11+a2], -sg*ci[l1*11+a2]); }
    }
    for (int j = 0; j <= 2*l2; ++j) {
        const int m = j - l2;
        if (m >= 0) f2v[j] = make_float2(cr[l2*11+m], ci[l2*11+m]);
        else { const int a2 = -m; const float sg = (a2&1)?-1.f:1.f;
               f2v[j] = make_float2(sg*cr[l2*11+a2], -sg*ci[l2*11+a2]); }
    }
    for (int j = 0; j <= 2*l; ++j) {
        const int m = j - l;
        if (m >= 0) flv[j] = make_float2(cr[l*11+m], ci[l*11+m]);
        else { const int a2 = -m; const float sg = (a2&1)?-1.f:1.f;
               flv[j] = make_float2(sg*cr[l*11+a2], -sg*ci[l*11+a2]); }
    }
    const float* cgp = cg + off + s;
    float r;
    switch (l) {
        case 0: r = core_fb<0>(f1v,f2v,flv,cgp,d1,d2,d); break;
        case 1: r = core_fb<1>(f1v,f2v,flv,cgp,d1,d2,d); break;
        case 2: r = core_fb<2>(f1v,f2v,flv,cgp,d1,d2,d); break;
        case 3: r = core_fb<3>(f1v,f2v,flv,cgp,d1,d2,d); break;
        case 4: r = core_fb<4>(f1v,f2v,flv,cgp,d1,d2,d); break;
        case 5: r = core_fb<5>(f1v,f2v,flv,cgp,d1,d2,d); break;
        case 6: r = core_fb<6>(f1v,f2v,flv,cgp,d1,d2,d); break;
        case 7: r = core_fb<7>(f1v,f2v,flv,cgp,d1,d2,d); break;
        case 8: r = core_fb<8>(f1v,f2v,flv,cgp,d1,d2,d); break;
        case 9: r = core_fb<9>(f1v,f2v,flv,cgp,d1,d2,d); break;
        default: r = core_fb<10>(f1v,f2v,flv,cgp,d1,d2,d); break;
    }
    out[(size_t)b * NCOLS + t] = r;
}

// ---------------------------------------------------------------------------
extern "C" void kernel_launch(void* const* d_in, const int* in_sizes, int n_in,
                              void* d_out, int out_size, void* d_ws, size_t ws_size,
                              hipStream_t stream)
{
    const float* cre = (const float*)d_in[0];
    const float* cim = (const float*)d_in[1];
    const float* cg  = (const float*)d_in[2];
    float* out = (float*)d_out;

    // compute cg16 total size (same walk as decode_pair_ext)
    long long c16_total = 0;
    for (int l1 = 0; l1 <= LMAX; ++l1)
        for (int l2 = l1; l2 <= LMAX; ++l2) {
            const int d    = (2*l1+1)*(2*l2+1);
            const int lmin = l2 - l1;
            const int lmx  = (l1 + l2 < LMAX) ? (l1 + l2) : LMAX;
            const int used = (lmx+1)*(lmx+1) - lmin*lmin;
            c16_total += (long long)((used+15)/16) * 16 * ((d+31)/32) * 32;
        }

    const size_t f_bytes = (size_t)NF * BATCH * sizeof(float2);   // 15,859,712
    const size_t need    = f_bytes + (size_t)c16_total * 2;       // ~17.8 MB

    if (ws_size >= need) {
        float2* f    = (float2*)d_ws;
        short*  cg16 = (short*)((char*)d_ws + f_bytes);
        prep    <<<dim3(512 + 7 * NPAIRS), 256, 0, stream>>>(cre, cim, cg, f, cg16);
        so3_mfma<<<dim3(BATCH/64, NPAIRS), 256, 0, stream>>>(f, cg16, out);
    } else {
        so3_tp_direct<<<dim3(BATCH/256, NCOLS), 256, 0, stream>>>(cre, cim, cg, out);
    }
}

// Round 9
// 341.303 us; speedup vs baseline: 3.5380x; 1.0187x over previous
//
#include <hip/hip_runtime.h>

#define LMAX   10
#define BATCH  16384
#define NCOLS  381
#define NF     121
#define NPAIRS 66

typedef __attribute__((ext_vector_type(8))) short    short8;
typedef __attribute__((ext_vector_type(8))) _Float16 half8;
typedef __attribute__((ext_vector_type(2))) _Float16 half2v;
typedef __attribute__((ext_vector_type(4))) float    floatx4;
typedef __attribute__((ext_vector_type(4))) unsigned uint4v;

__device__ __forceinline__ short f32_to_f16_bits(float x) {
    return __builtin_bit_cast(short, (_Float16)x);   // RNE
}

// heavy-pairs-first dispatch order (sorted by descending npan*NT)
__device__ const int kPairOrder[NPAIRS] = {
    65,64,63,62,61,60,58,59,56,57,55,52,53,54,49,51,47,50,48,46,
    43,44,41,42,40,45,36,34,39,37,35,27,33,38,29,25,26,28,32,18,
    19,24,30,31,15,16,17,20,22,23,14, 8, 9,10,21, 0, 1, 2, 3, 4,
     5, 6, 7,11,12,13
};

// pair index p -> (l1, l2, cg offset, first output column, cg16 offset)
__device__ __forceinline__ void decode_pair_ext(int p, int& l1, int& l2,
                                                long long& off, int& colbase,
                                                int& c16off)
{
    long long o = 0; int cb = 0, c16 = 0, idx = 0;
    for (int a = 0; a <= LMAX; ++a) {
        for (int bq = a; bq <= LMAX; ++bq) {
            const int d    = (2*a+1)*(2*bq+1);
            const int lmin = bq - a;
            const int lmx  = (a + bq < LMAX) ? (a + bq) : LMAX;
            const int used = (lmx+1)*(lmx+1) - lmin*lmin;
            const int npan = (d + 31) >> 5;
            const int nt   = (used + 15) >> 4;
            if (idx == p) { l1 = a; l2 = bq; off = o; colbase = cb; c16off = c16; return; }
            o += (long long)d * d; cb += lmx - lmin + 1;
            c16 += nt * 16 * npan * 32; ++idx;
        }
    }
    l1 = l2 = 0; off = 0; colbase = 0; c16off = 0;
}

// ---------------------------------------------------------------------------
// prep kernel = build_f (coalesced, LDS-staged) + cg_to_f16 (LDS-transposed),
// fused on a 1D grid.
//  blocks [0,512):   build_f, btile = bid*32.
//  blocks [512,974): cg_to_f16 -> [n][K32] layout.  NEW (r9): gather-coalesced
//    reads -> LDS tile L[128][72] halves -> k-contiguous short8 writes (128B
//    segments) instead of 2B stores at 896B stride (16x fewer transactions).
// ---------------------------------------------------------------------------
__global__ __launch_bounds__(256) void prep(const float* __restrict__ cre,
                                            const float* __restrict__ cim,
                                            const float* __restrict__ cg,
                                            float2* __restrict__ f,
                                            short* __restrict__ cg16)
{
    __shared__ __align__(16) char pbuf[30976];    // union{ sr+si , L tile }
    const int tid = threadIdx.x;

    if (blockIdx.x < 512) {
        // ---- build_f part ----
        float* sr = (float*)pbuf;                  // [32*121]
        float* si = sr + 32 * 121;                 // [32*121]
        const int btile = blockIdx.x * 32;
        for (int t = tid; t < 32 * 121; t += 256) {
            sr[t] = cre[(size_t)btile * 121 + t];
            si[t] = cim[(size_t)btile * 121 + t];
        }
        __syncthreads();
        for (int task = tid; task < 32 * 121; task += 256) {
            const int row = task & 31;
            const int idx = task >> 5;
            int l = (int)sqrtf((float)idx + 0.5f);
            if (l * l > idx) --l;
            if ((l + 1) * (l + 1) <= idx) ++l;
            const int m = idx - l * l - l;
            const float* crow  = sr + row * 121 + l * 11;
            const float* cirow = si + row * 121 + l * 11;
            float re, im;
            if (m >= 0) { re = crow[m]; im = cirow[m]; }
            else {
                const int a = -m;
                const float sg = (a & 1) ? -1.0f : 1.0f;
                re = sg * crow[a]; im = -sg * cirow[a];
            }
            f[(size_t)idx * BATCH + btile + row] = make_float2(re, im);
        }
        return;
    }

    // ---- cg_to_f16 part ([n][K32] layout, LDS-transposed for coalesced writes)
    const int bid2 = blockIdx.x - 512;
    const int pair = bid2 / 7;
    const int xk   = bid2 - pair * 7;

    int l1, l2, colbase, c16off; long long off;
    decode_pair_ext(pair, l1, l2, off, colbase, c16off);
    const int d    = (2*l1+1)*(2*l2+1);
    const int lmin = l2 - l1;
    const int lmx  = (l1 + l2 < LMAX) ? (l1 + l2) : LMAX;
    const int used = (lmx+1)*(lmx+1) - lmin*lmin;
    const int npan = (d + 31) >> 5;
    const int nt   = (used + 15) >> 4;
    const int K32  = npan * 32;
    const int kbase = xk * 64;
    if (kbase >= K32) return;                     // uniform per block
    const int kend  = (kbase + 64 < K32) ? kbase + 64 : K32;
    const int usedp = nt * 16;

    short* L = (short*)pbuf;                      // [128][72] halves (18432B)

    // producer: coalesced gather (nn across lanes), write LDS tile
    {
        const int nn = tid & 127;
        const int kh = tid >> 7;
        for (int k = kbase + kh; k < kend; k += 2) {
            float v = 0.f;
            if (nn < used && k < d)
                v = cg[off + (size_t)k * d + nn];
            L[nn * 72 + (k - kbase)] = f32_to_f16_bits(v);
        }
    }
    __syncthreads();

    // consumer: k-contiguous 16B stores (8 lanes -> one 128B segment)
    {
        const int oct = tid & 7;                  // k-octet within the 64-tile
        const int ng  = tid >> 3;                 // 0..31
        const int kk  = kbase + oct * 8;
        if (kk < K32) {
            for (int nn = ng; nn < usedp; nn += 32) {
                const short8 vv = *(const short8*)&L[nn * 72 + oct * 8];
                *(short8*)(cg16 + (size_t)c16off + (size_t)nn * K32 + kk) = vv;
            }
        }
    }
}

// ---------------------------------------------------------------------------
// MFMA pair kernel, round 21 = round 20 + ILP epilogue:
//  - r1/r3 panel loop (verified): f12 [row][FS=51] replicated layout,
//    guard-free A frags, B [128][32] XOR-swizzled LDS-broadcast staging,
//    double-buffered, one barrier per panel, NT up to 8.
//  - NEW epilogue: r1's two-pass task structure, but the j-loop is a
//    compile-time unroll-21 with value predication. All 21 f loads and T
//    reads are provably in-bounds (l*l+20 <= 120 < 121; sl+20 <= 120 < 123),
//    so loads issue unconditionally (full ILP) and only the multiplicand is
//    selected to 0 for j >= W. Kills the 21-deep load->fma serial chain.
//  - (256,4): r2 proved (256,5) spills NT=7/8. r7 proved narrow-NT panels
//    are overhead-dominated regardless of occupancy. Do not re-try either.
// LDS union: { f12 13056 + B0/B1 2x8192 = 29440 , T 31488 } = 31488B.
// ---------------------------------------------------------------------------
template<int NT, bool BIGD2>
__device__ __forceinline__ void pair_body(const float2* __restrict__ f,
                                          const short* __restrict__ cg16,
                                          float* __restrict__ out,
                                          short* smem, int btile,
                                          int l1, int l2, int c16off, int colbase)
{
    const int d1 = 2*l1 + 1, d2 = 2*l2 + 1, d = d1 * d2;
    const int lmin = l2 - l1;
    const int lmx  = (l1 + l2 < LMAX) ? (l1 + l2) : LMAX;
    const int n_l  = lmx - lmin + 1;
    const int q1 = l1*l1, q2 = l2*l2;
    const int npan = (d + 31) >> 5;
    const int K32  = npan * 32;

    const int tid  = threadIdx.x;
    const int lane = tid & 63;
    const int w    = tid >> 6;        // wave 0..3 -> M-tile
    const int quad = lane >> 4;
    const int r16  = lane & 15;

    constexpr int FS = 51;                         // f12 row stride (dwords, odd)
    unsigned* f12 = (unsigned*)smem;               // [64][FS] packed half2 {re,im}
    short* B0 = smem + 64 * FS * 2;                // 13056 B in (16B aligned)
    short* B1 = B0 + 128 * 32;                     // each [128 rows][32 k] swizzled

    // ---- stage f1 | replicated f2 per batch row (fills ALL FS slots) ----
    {
        const int srow = tid & 63;
        unsigned* frw = f12 + srow * FS;
        const float2* f1p = f + (size_t)q1 * BATCH + btile + srow;
        const float2* f2p = f + (size_t)q2 * BATCH + btile + srow;
        for (int mm = tid >> 6; mm < FS; mm += 4) {
            float2 v;
            if (mm < d1) v = f1p[(size_t)mm * BATCH];
            else {
                int m2s = mm - d1;
                while (m2s >= d2) m2s -= d2;
                v = f2p[(size_t)m2s * BATCH];
            }
            half2v h; h.x = (_Float16)v.x; h.y = (_Float16)v.y;
            frw[mm] = __builtin_bit_cast(unsigned, h);
        }
    }

    const short* cgbase = cg16 + (size_t)c16off;
    const int nchunk = NT * 64;                    // 16B chunks per panel (<=512)

    // B prefetch: issue (global->regs) and commit (regs->LDS); XOR swizzle
    short8 pf0, pf1;
    const int ch0 = tid, ch1 = tid + 256;
    const int nr0 = ch0 >> 2, cc0 = ch0 & 3;
    const int nr1 = ch1 >> 2, cc1 = ch1 & 3;
    const size_t so0 = (size_t)nr0 * K32 + cc0 * 8;
    const size_t so1 = (size_t)nr1 * K32 + cc1 * 8;
    const int bo0 = nr0 * 32 + (((cc0 + (nr0 >> 1)) & 3) << 3);
    const int bo1 = nr1 * 32 + (((cc1 + (nr1 >> 1)) & 3) << 3);

    // panel 0 into B0 (overlaps f12 staging above; barrier covers both)
    // guards fold to constant-true for NT>=4 / NT>=8
    if (NT >= 4 || ch0 < nchunk) pf0 = *(const short8*)(cgbase + so0);
    if (NT >= 8 || ch1 < nchunk) pf1 = *(const short8*)(cgbase + so1);
    if (NT >= 4 || ch0 < nchunk) *(short8*)&B0[bo0] = pf0;
    if (NT >= 8 || ch1 < nchunk) *(short8*)&B0[bo1] = pf1;
    __syncthreads();

    floatx4 accR[NT], accI[NT];
#pragma unroll
    for (int i = 0; i < NT; ++i) {
        accR[i] = (floatx4)0.0f; accI[i] = (floatx4)0.0f;
    }

    const int arow = w * 16 + r16;                 // this lane's batch row
    const unsigned* frow = f12 + arow * FS;
    const int bswz = ((quad + (r16 >> 1)) & 3) << 3;   // B read chunk swizzle

    // incremental k -> (m1, m2) for this lane's quad (one divide per block)
    const int k0q = quad * 8;
    int m1 = k0q / d2;
    int m2 = k0q - m1 * d2;
    const int q32 = 32 / d2;
    const int r32 = 32 - q32 * d2;

    for (int pan = 0; pan < npan; ++pan) {
        short* Bc = (pan & 1) ? B1 : B0;
        short* Bn = (pan & 1) ? B0 : B1;

        // ---- issue next panel's global loads (no wait yet) ----
        const bool more = (pan + 1) < npan;
        if (more) {
            const size_t kn = (size_t)(pan + 1) << 5;
            if (NT >= 4 || ch0 < nchunk) pf0 = *(const short8*)(cgbase + so0 + kn);
            if (NT >= 8 || ch1 < nchunk) pf1 = *(const short8*)(cgbase + so1 + kn);
        }

        // ---- A fragments (tp in f16), guard-free ----
        unsigned ar[4], ai[4];
        {
            const unsigned* cb = frow + d1 + m2;   // 8 contiguous dwords
            if (BIGD2) {
                // d2>=9: at most one m1 boundary inside the 8-group
                const unsigned a0 = frow[m1];
                const unsigned a1 = frow[m1 + 1];
                const int wpos = d2 - m2;          // first j using a1
#pragma unroll
                for (int t = 0; t < 4; ++t) {
                    unsigned r01[2];
#pragma unroll
                    for (int u = 0; u < 2; ++u) {
                        const int j = 2*t + u;
                        const unsigned ad = (j >= wpos) ? a1 : a0;
                        const half2v a = __builtin_bit_cast(half2v, ad);
                        const half2v c = __builtin_bit_cast(half2v, cb[j]);
                        const _Float16 tr = a.x * c.x - a.y * c.y;
                        const _Float16 ti = a.x * c.y + a.y * c.x;
                        half2v rr; rr.x = tr; rr.y = ti;
                        r01[u] = __builtin_bit_cast(unsigned, rr);
                    }
                    ar[t] = (r01[0] & 0xffffu) | (r01[1] << 16);
                    ai[t] = (r01[0] >> 16)    | (r01[1] & 0xffff0000u);
                }
            } else {
                // small d2 (<=7): per-j a walk; c still via replication
                int mm1 = m1, tcnt = m2;
#pragma unroll
                for (int t = 0; t < 4; ++t) {
                    unsigned r01[2];
#pragma unroll
                    for (int u = 0; u < 2; ++u) {
                        const int j = 2*t + u;
                        const half2v a = __builtin_bit_cast(half2v, frow[mm1]);
                        const half2v c = __builtin_bit_cast(half2v, cb[j]);
                        const _Float16 tr = a.x * c.x - a.y * c.y;
                        const _Float16 ti = a.x * c.y + a.y * c.x;
                        half2v rr; rr.x = tr; rr.y = ti;
                        r01[u] = __builtin_bit_cast(unsigned, rr);
                        if (++tcnt == d2) { tcnt = 0; ++mm1; }
                    }
                    ar[t] = (r01[0] & 0xffffu) | (r01[1] << 16);
                    ai[t] = (r01[0] >> 16)    | (r01[1] & 0xffff0000u);
                }
            }
        }
        const half8 are = __builtin_bit_cast(half8, (uint4v){ar[0], ar[1], ar[2], ar[3]});
        const half8 aim = __builtin_bit_cast(half8, (uint4v){ai[0], ai[1], ai[2], ai[3]});

        // advance (m1,m2) by K=32 for next panel
        m1 += q32; m2 += r32;
        if (m2 >= d2) { m2 -= d2; ++m1; }

        // ---- MFMA from current LDS buffer ----
#pragma unroll
        for (int n0 = 0; n0 < NT; ++n0) {
            const short8 b16 = *(const short8*)&Bc[(n0 * 16 + r16) * 32 + bswz];
            const half8 bb = __builtin_bit_cast(half8, b16);
            accR[n0] = __builtin_amdgcn_mfma_f32_16x16x32_f16(are, bb, accR[n0], 0, 0, 0);
            accI[n0] = __builtin_amdgcn_mfma_f32_16x16x32_f16(aim, bb, accI[n0], 0, 0, 0);
        }

        // ---- commit next panel to alternate buffer, one barrier ----
        if (more) {
            if (NT >= 4 || ch0 < nchunk) *(short8*)&Bn[bo0] = pf0;
            if (NT >= 8 || ch1 < nchunk) *(short8*)&Bn[bo1] = pf1;
        }
        __syncthreads();
    }

    // ---- two-pass fp32 epilogue, unroll-21 value-predicated (r9) ----
    // C/D frag layout: col = lane&15, row = quad*4 + reg.
    float* T = (float*)smem;                  // [64][123] fp32
    const int ntask = 64 * n_l;
    float part[3] = {0.f, 0.f, 0.f};

    // pass 1: real
#pragma unroll
    for (int n0 = 0; n0 < NT; ++n0)
#pragma unroll
        for (int r = 0; r < 4; ++r) {
            const int col = n0*16 + r16;
            if (col < 123)
                T[(w*16 + quad*4 + r) * 123 + col] = accR[n0][r];
        }
    __syncthreads();
    {
        int it = 0;
        for (int task = tid; task < ntask; task += 256, ++it) {
            const int trow = task & 63;
            const int li   = task >> 6;
            const int l    = lmin + li;
            const int sl   = l*l - lmin*lmin;
            const int W    = 2*l + 1;
            const float* Trow = T + trow * 123 + sl;
            const float2* fb = f + (size_t)(l*l) * BATCH + (btile + trow);
            float a0 = 0.f, a1 = 0.f;
#pragma unroll
            for (int j = 0; j < 21; j += 2) {
                const float  tv0 = (j < W) ? Trow[j] : 0.f;
                const float2 fv0 = fb[(size_t)j * BATCH];
                a0 = fmaf(tv0, fv0.x, a0);
                if (j + 1 < 21) {
                    const float  tv1 = (j + 1 < W) ? Trow[j + 1] : 0.f;
                    const float2 fv1 = fb[(size_t)(j + 1) * BATCH];
                    a1 = fmaf(tv1, fv1.x, a1);
                }
            }
            part[it] = a0 + a1;
        }
    }
    __syncthreads();

    // pass 2: imaginary
#pragma unroll
    for (int n0 = 0; n0 < NT; ++n0)
#pragma unroll
        for (int r = 0; r < 4; ++r) {
            const int col = n0*16 + r16;
            if (col < 123)
                T[(w*16 + quad*4 + r) * 123 + col] = accI[n0][r];
        }
    __syncthreads();
    {
        int it = 0;
        for (int task = tid; task < ntask; task += 256, ++it) {
            const int trow = task & 63;
            const int li   = task >> 6;
            const int l    = lmin + li;
            const int sl   = l*l - lmin*lmin;
            const int W    = 2*l + 1;
            const float* Trow = T + trow * 123 + sl;
            const float2* fb = f + (size_t)(l*l) * BATCH + (btile + trow);
            float a0 = part[it], a1 = 0.f;
#pragma unroll
            for (int j = 0; j < 21; j += 2) {
                const float  tv0 = (j < W) ? Trow[j] : 0.f;
                const float2 fv0 = fb[(size_t)j * BATCH];
                a0 = fmaf(tv0, fv0.y, a0);
                if (j + 1 < 21) {
                    const float  tv1 = (j + 1 < W) ? Trow[j + 1] : 0.f;
                    const float2 fv1 = fb[(size_t)(j + 1) * BATCH];
                    a1 = fmaf(tv1, fv1.y, a1);
                }
            }
            out[(size_t)(btile + trow) * NCOLS + colbase + li] = a0 + a1;
        }
    }
}

__global__ __launch_bounds__(256, 4) void so3_mfma(const float2* __restrict__ f,
                                                   const short* __restrict__ cg16,
                                                   float* __restrict__ out)
{
    __shared__ __align__(16) short smem[15744];   // 31.5 KB
    const int btile = blockIdx.x * 64;
    const int p     = kPairOrder[blockIdx.y];     // heavy pairs first
    int l1, l2, colbase, c16off; long long off;
    decode_pair_ext(p, l1, l2, off, colbase, c16off);
    const int lmin = l2 - l1;
    const int lmx  = (l1 + l2 < LMAX) ? (l1 + l2) : LMAX;
    const int used = (lmx+1)*(lmx+1) - lmin*lmin;
    const int nt   = (used + 15) >> 4;
    if (l2 >= 4) {   // d2 >= 9 -> single-boundary A path
        switch (nt) {
            case 1: pair_body<1,true>(f, cg16, out, smem, btile, l1, l2, c16off, colbase); break;
            case 2: pair_body<2,true>(f, cg16, out, smem, btile, l1, l2, c16off, colbase); break;
            case 3: pair_body<3,true>(f, cg16, out, smem, btile, l1, l2, c16off, colbase); break;
            case 4: pair_body<4,true>(f, cg16, out, smem, btile, l1, l2, c16off, colbase); break;
            case 5: pair_body<5,true>(f, cg16, out, smem, btile, l1, l2, c16off, colbase); break;
            case 6: pair_body<6,true>(f, cg16, out, smem, btile, l1, l2, c16off, colbase); break;
            case 7: pair_body<7,true>(f, cg16, out, smem, btile, l1, l2, c16off, colbase); break;
            default: pair_body<8,true>(f, cg16, out, smem, btile, l1, l2, c16off, colbase); break;
        }
    } else {         // l2 <= 3 -> nt <= 4
        switch (nt) {
            case 1: pair_body<1,false>(f, cg16, out, smem, btile, l1, l2, c16off, colbase); break;
            case 2: pair_body<2,false>(f, cg16, out, smem, btile, l1, l2, c16off, colbase); break;
            case 3: pair_body<3,false>(f, cg16, out, smem, btile, l1, l2, c16off, colbase); break;
            default: pair_body<4,false>(f, cg16, out, smem, btile, l1, l2, c16off, colbase); break;
        }
    }
}

// ---------------------------------------------------------------------------
// Full fallback (fp32 VALU, no workspace). Round-5 copy.
// ---------------------------------------------------------------------------
template<int L>
__device__ __forceinline__ float core_fb(const float2* f1v, const float2* f2v,
                                         const float2* flv,
                                         const float* __restrict__ cgp,
                                         int d1, int d2, int d)
{
    constexpr int W = 2*L + 1;
    float accr[W], acci[W];
#pragma unroll
    for (int k = 0; k < W; ++k) { accr[k] = 0.f; acci[k] = 0.f; }
    for (int m1 = 0; m1 < d1; ++m1) {
        const float2 a = f1v[m1];
        const float* rowbase = cgp + (size_t)m1 * d2 * d;
        for (int m2 = 0; m2 < d2; ++m2) {
            const float2 bb = f2v[m2];
            const float tr = a.x*bb.x - a.y*bb.y;
            const float ti = a.x*bb.y + a.y*bb.x;
            const float* row = rowbase + (size_t)m2 * d;
#pragma unroll
            for (int k = 0; k < W; ++k) {
                accr[k] = fmaf(tr, row[k], accr[k]);
                acci[k] = fmaf(ti, row[k], acci[k]);
            }
        }
    }
    float orr = 0.f;
#pragma unroll
    for (int k = 0; k < W; ++k)
        orr = fmaf(accr[k], flv[k].x, fmaf(acci[k], flv[k].y, orr));
    return orr;
}

__global__ __launch_bounds__(256) void so3_tp_direct(const float* __restrict__ cre,
                                                     const float* __restrict__ cim,
                                                     const float* __restrict__ cg,
                                                     float* __restrict__ out)
{
    const int b = blockIdx.x * blockDim.x + threadIdx.x;
    const int t = blockIdx.y;
    int l1 = 0, l2 = 0, l = 0; long long off = 0;
    {
        int tt = t; long long o = 0;
        bool found = false;
        for (int a = 0; a <= LMAX && !found; ++a)
            for (int bq = a; bq <= LMAX && !found; ++bq) {
                const int d = (2*a+1)*(2*bq+1);
                const int lmin = bq - a;
                const int lmx = (a+bq < LMAX) ? (a+bq) : LMAX;
                const int cnt = lmx - lmin + 1;
                if (tt < cnt) { l1 = a; l2 = bq; l = lmin + tt; off = o; found = true; }
                else { tt -= cnt; o += (long long)d*d; }
            }
    }
    const int d1 = 2*l1+1, d2 = 2*l2+1, d = d1*d2;
    const int lmin = l2 - l1;
    const int s = l*l - lmin*lmin;

    const float* cr = cre + (size_t)b * 121;
    const float* ci = cim + (size_t)b * 121;
    float2 f1v[21], f2v[21], flv[21];
    for (int j = 0; j <= 2*l1; ++j) {
        const int m = j - l1;
        if (m >= 0) f1v[j] = make_float2(cr[l1*11+m], ci[l1*11+m]);
        else { const int a2 = -m; const float sg = (a2&1)?-1.f:1.f;
               f1v[j] = make_float2(sg*cr[l1*11+a2], -sg*ci[l1*11+a2]); }
    }
    for (int j = 0; j <= 2*l2; ++j) {
        const int m = j - l2;
        if (m >= 0) f2v[j] = make_float2(cr[l2*11+m], ci[l2*11+m]);
        else { const int a2 = -m; const float sg = (a2&1)?-1.f:1.f;
               f2v[j] = make_float2(sg*cr[l2*11+a2], -sg*ci[l2*11+a2]); }
    }
    for (int j = 0; j <= 2*l; ++j) {
        const int m = j - l;
        if (m >= 0) flv[j] = make_float2(cr[l*11+m], ci[l*11+m]);
        else { const int a2 = -m; const float sg = (a2&1)?-1.f:1.f;
               flv[j] = make_float2(sg*cr[l*11+a2], -sg*ci[l*11+a2]); }
    }
    const float* cgp = cg + off + s;
    float r;
    switch (l) {
        case 0: r = core_fb<0>(f1v,f2v,flv,cgp,d1,d2,d); break;
        case 1: r = core_fb<1>(f1v,f2v,flv,cgp,d1,d2,d); break;
        case 2: r = core_fb<2>(f1v,f2v,flv,cgp,d1,d2,d); break;
        case 3: r = core_fb<3>(f1v,f2v,flv,cgp,d1,d2,d); break;
        case 4: r = core_fb<4>(f1v,f2v,flv,cgp,d1,d2,d); break;
        case 5: r = core_fb<5>(f1v,f2v,flv,cgp,d1,d2,d); break;
        case 6: r = core_fb<6>(f1v,f2v,flv,cgp,d1,d2,d); break;
        case 7: r = core_fb<7>(f1v,f2v,flv,cgp,d1,d2,d); break;
        case 8: r = core_fb<8>(f1v,f2v,flv,cgp,d1,d2,d); break;
        case 9: r = core_fb<9>(f1v,f2v,flv,cgp,d1,d2,d); break;
        default: r = core_fb<10>(f1v,f2v,flv,cgp,d1,d2,d); break;
    }
    out[(size_t)b * NCOLS + t] = r;
}

// ---------------------------------------------------------------------------
extern "C" void kernel_launch(void* const* d_in, const int* in_sizes, int n_in,
                              void* d_out, int out_size, void* d_ws, size_t ws_size,
                              hipStream_t stream)
{
    const float* cre = (const float*)d_in[0];
    const float* cim = (const float*)d_in[1];
    const float* cg  = (const float*)d_in[2];
    float* out = (float*)d_out;

    // compute cg16 total size (same walk as decode_pair_ext)
    long long c16_total = 0;
    for (int l1 = 0; l1 <= LMAX; ++l1)
        for (int l2 = l1; l2 <= LMAX; ++l2) {
            const int d    = (2*l1+1)*(2*l2+1);
            const int lmin = l2 - l1;
            const int lmx  = (l1 + l2 < LMAX) ? (l1 + l2) : LMAX;
            const int used = (lmx+1)*(lmx+1) - lmin*lmin;
            c16_total += (long long)((used+15)/16) * 16 * ((d+31)/32) * 32;
        }

    const size_t f_bytes = (size_t)NF * BATCH * sizeof(float2);   // 15,859,712
    const size_t need    = f_bytes + (size_t)c16_total * 2;       // ~17.8 MB

    if (ws_size >= need) {
        float2* f    = (float2*)d_ws;
        short*  cg16 = (short*)((char*)d_ws + f_bytes);
        prep    <<<dim3(512 + 7 * NPAIRS), 256, 0, stream>>>(cre, cim, cg, f, cg16);
        so3_mfma<<<dim3(BATCH/64, NPAIRS), 256, 0, stream>>>(f, cg16, out);
    } else {
        so3_tp_direct<<<dim3(BATCH/256, NCOLS), 256, 0, stream>>>(cre, cim, cg, out);
    }
}